// Round 7
// baseline (160.135 us; speedup 1.0000x reference)
//
#include <hip/hip_runtime.h>
#include <hip/hip_bf16.h>

#define SCALE 3.5f
#define TJ 512            // square tile size (points)
#define THREADS 256       // 4 waves per block
#define NA 8              // A-frags per wave: 8*16 = 128 i-pts; 4 waves = 512
#define EDGE_BLOCKS 256
#define MAGIC 0x13572468  // != 0xAAAAAAAA poison

typedef __attribute__((ext_vector_type(8))) short short8;   // 8 bf16 = 4 VGPRs
typedef __attribute__((ext_vector_type(4))) short short4v;  // 4 bf16 = 2 VGPRs
typedef __attribute__((ext_vector_type(4))) float float4v;

// fp32 -> bf16 round-to-nearest-even (bit trick; inputs finite)
__device__ inline short bfh(float v) {
    union { float f; unsigned u; } x; x.f = v;
    unsigned r = (x.u + 0x7fffu + ((x.u >> 16) & 1u)) >> 16;
    return (short)r;
}
__device__ inline float bff(short s) {
    union { float f; unsigned u; } x; x.u = ((unsigned)(unsigned short)s) << 16;
    return x.f;
}

// ws: double pZ[nbBlocks] | double pC[EDGE_BLOCKS] | double pS[EDGE_BLOCKS]
//     | int flags[EDGE_BLOCKS + nbBlocks]   (0xAA poison != MAGIC)

__global__ __launch_bounds__(THREADS, 8)   // 32 waves/CU; VGPR cap 64
void fused_kernel(const float* __restrict__ emb,
                  const float* __restrict__ p,
                  const int* __restrict__ heads,
                  const int* __restrict__ tails,
                  int e, int n, int nt, int nbBlocks,
                  double* __restrict__ pZ,
                  double* __restrict__ pC,
                  double* __restrict__ pS,
                  int* __restrict__ flags,
                  float* __restrict__ out) {
    const int bid = blockIdx.x;
    const float2* e2 = (const float2*)emb;
    const int lane = threadIdx.x & 63, wid = threadIdx.x >> 6;

    if (bid >= EDGE_BLOCKS && bid < EDGE_BLOCKS + nbBlocks) {
        // ================= n-body tile (Z) via MFMA =================
        // t_ij = 1+|pi-pj|^2 = dot(A_i, B_j), A=[-2x,-2y,1+|p|^2,1], B=[x,y,1,|p|^2]
        // bf16 hi/lo split. Doubling trick (no zero-padding, all 32 k-slots live):
        //   quads 0,2: A=[Ahi|Ahi]; quads 1,3: A=[Alo|Alo]; all quads: B=[Bhi|Blo]
        //   => D = 2*(Ahi+Alo)·(Bhi+Blo) = 2*t exactly; fold /2 into final weight.
        const int b = bid - EDGE_BLOCKS;
        int ti = (int)((2.0f * nt + 1.0f -
                        sqrtf((float)((2 * nt + 1) * (2 * nt + 1) - 8 * b))) * 0.5f);
        while ((ti + 1) * nt - ((ti + 1) * ti) / 2 <= b) ++ti;
        while (ti * nt - (ti * (ti - 1)) / 2 > b) --ti;
        const int tj = ti + (b - (ti * nt - (ti * (ti - 1)) / 2));
        const int ibase = ti * TJ, jbase = tj * TJ;

        __shared__ __align__(16) short8 aHL[TJ];  // [ah,bh,ch,1 | al,bl,cl,0]
        __shared__ __align__(16) short8 bHL[TJ];  // [xh,yh,1,fh | xl,yl,0,fl]
        const short ONE = (short)0x3F80;  // bf16 1.0
        for (int k = threadIdx.x; k < TJ; k += THREADS) {
            float2 v = e2[ibase + k];
            float X = v.x * SCALE, Y = v.y * SCALE;
            float A = -2.0f * X, B = -2.0f * Y, C = fmaf(X, X, fmaf(Y, Y, 1.0f));
            short ah = bfh(A), bh = bfh(B), ch = bfh(C);
            aHL[k] = (short8){ah, bh, ch, ONE,
                              bfh(A - bff(ah)), bfh(B - bff(bh)), bfh(C - bff(ch)), 0};
            float2 u = e2[jbase + k];
            float Xj = u.x * SCALE, Yj = u.y * SCALE, F = fmaf(Xj, Xj, Yj * Yj);
            short xh = bfh(Xj), yh = bfh(Yj), fh = bfh(F);
            bHL[k] = (short8){xh, yh, ONE, fh,
                              bfh(Xj - bff(xh)), bfh(Yj - bff(yh)), 0, bfh(F - bff(fh))};
        }
        __syncthreads();

        const int m = lane & 15, q = lane >> 4;

        // A-frags: wave wid owns i-points wid*128 + a*16 + m; parity picks hi/lo
        const short4v* aP = (const short4v*)aHL;
        short8 afr[NA];
#pragma unroll
        for (int a = 0; a < NA; ++a) {
            short4v h = aP[((wid * 128 + a * 16 + m) << 1) + (q & 1)];
            afr[a] = __builtin_shufflevector(h, h, 0, 1, 2, 3, 0, 1, 2, 3);
        }

        const float4v cz = {0.0f, 0.0f, 0.0f, 0.0f};
        float accv = 0.0f;
        for (int g = 0; g < TJ / 16; ++g) {
            short8 bfr = bHL[g * 16 + m];   // same for all quads (broadcast)
#pragma unroll
            for (int a = 0; a < NA; ++a) {
                float4v D = __builtin_amdgcn_mfma_f32_16x16x32_bf16(afr[a], bfr,
                                                                    cz, 0, 0, 0);
                // 4-way rcp combine on D=2t: sum(1/D) = (1/2) sum(1/t)
                float t0 = D[0], t1 = D[1], t2 = D[2], t3 = D[3];
                float ab = t0 * t1, cd = t2 * t3;
                float num = fmaf(t2 + t3, ab, (t0 + t1) * cd);
                accv = fmaf(num, __builtin_amdgcn_rcpf(ab * cd), accv);
            }
        }
#pragma unroll
        for (int off = 32; off > 0; off >>= 1)
            accv += __shfl_down(accv, off, 64);

        __shared__ float nred[THREADS / 64];
        if (lane == 0) nred[wid] = accv;
        __syncthreads();
        if (threadIdx.x == 0) {
            float tot = 0.0f;
#pragma unroll
            for (int w = 0; w < THREADS / 64; ++w) tot += nred[w];
            // x2 undoes the doubling trick; extra x2 for off-diagonal tiles
            double val = (ti == tj ? 2.0 : 4.0) * (double)tot;
            __hip_atomic_store(&pZ[b], val, __ATOMIC_RELAXED, __HIP_MEMORY_SCOPE_AGENT);
            __hip_atomic_store(&flags[bid], MAGIC, __ATOMIC_RELEASE,
                               __HIP_MEMORY_SCOPE_AGENT);
        }
    } else if (bid < EDGE_BLOCKS) {
        // ================= edge (attractive + entropy) =================
        const int4* h4 = (const int4*)heads;
        const int4* t4 = (const int4*)tails;
        const float4* p4 = (const float4*)p;
        const int e4 = e >> 2;
        const int stride = EDGE_BLOCKS * THREADS;
        float accC = 0.0f, accS = 0.0f;
        for (int idx = bid * THREADS + threadIdx.x; idx < e4; idx += stride) {
            int4 h = h4[idx];
            int4 t = t4[idx];
            float4 pv = p4[idx];
            {
                float2 a = e2[h.x], b = e2[t.x];
                float dx = a.x - b.x, dy = a.y - b.y;
                float sq = fmaf(dx, dx, dy * dy) * (SCALE * SCALE);
                accC += pv.x * __logf(pv.x * (1.0f + sq));
                accS += pv.x;
            }
            {
                float2 a = e2[h.y], b = e2[t.y];
                float dx = a.x - b.x, dy = a.y - b.y;
                float sq = fmaf(dx, dx, dy * dy) * (SCALE * SCALE);
                accC += pv.y * __logf(pv.y * (1.0f + sq));
                accS += pv.y;
            }
            {
                float2 a = e2[h.z], b = e2[t.z];
                float dx = a.x - b.x, dy = a.y - b.y;
                float sq = fmaf(dx, dx, dy * dy) * (SCALE * SCALE);
                accC += pv.z * __logf(pv.z * (1.0f + sq));
                accS += pv.z;
            }
            {
                float2 a = e2[h.w], b = e2[t.w];
                float dx = a.x - b.x, dy = a.y - b.y;
                float sq = fmaf(dx, dx, dy * dy) * (SCALE * SCALE);
                accC += pv.w * __logf(pv.w * (1.0f + sq));
                accS += pv.w;
            }
        }
        for (int idx = (e4 << 2) + bid * THREADS + threadIdx.x; idx < e; idx += stride) {
            int h = heads[idx], t = tails[idx];
            float pv = p[idx];
            float2 a = e2[h], b = e2[t];
            float dx = a.x - b.x, dy = a.y - b.y;
            float sq = fmaf(dx, dx, dy * dy) * (SCALE * SCALE);
            accC += pv * __logf(pv * (1.0f + sq));
            accS += pv;
        }
#pragma unroll
        for (int off = 32; off > 0; off >>= 1) {
            accC += __shfl_down(accC, off, 64);
            accS += __shfl_down(accS, off, 64);
        }
        __shared__ float rc[THREADS / 64], rs[THREADS / 64];
        if (lane == 0) { rc[wid] = accC; rs[wid] = accS; }
        __syncthreads();
        if (threadIdx.x == 0) {
            float tc = 0.0f, ts = 0.0f;
#pragma unroll
            for (int w = 0; w < THREADS / 64; ++w) { tc += rc[w]; ts += rs[w]; }
            __hip_atomic_store(&pC[bid], (double)tc, __ATOMIC_RELAXED,
                               __HIP_MEMORY_SCOPE_AGENT);
            __hip_atomic_store(&pS[bid], (double)ts, __ATOMIC_RELAXED,
                               __HIP_MEMORY_SCOPE_AGENT);
            __hip_atomic_store(&flags[bid], MAGIC, __ATOMIC_RELEASE,
                               __HIP_MEMORY_SCOPE_AGENT);
        }
    } else {
        // ================= finalize (spin-wait producers, reduce, emit) =========
        const int nprod = EDGE_BLOCKS + nbBlocks;
        double lC = 0.0, lS = 0.0, lZ = 0.0;
        for (int b = threadIdx.x; b < nprod; b += THREADS) {
            while (__hip_atomic_load(&flags[b], __ATOMIC_ACQUIRE,
                                     __HIP_MEMORY_SCOPE_AGENT) != MAGIC)
                __builtin_amdgcn_s_sleep(8);
            if (b < EDGE_BLOCKS) {
                lC += __hip_atomic_load(&pC[b], __ATOMIC_RELAXED,
                                        __HIP_MEMORY_SCOPE_AGENT);
                lS += __hip_atomic_load(&pS[b], __ATOMIC_RELAXED,
                                        __HIP_MEMORY_SCOPE_AGENT);
            } else {
                lZ += __hip_atomic_load(&pZ[b - EDGE_BLOCKS], __ATOMIC_RELAXED,
                                        __HIP_MEMORY_SCOPE_AGENT);
            }
        }
#pragma unroll
        for (int off = 32; off > 0; off >>= 1) {
            lC += __shfl_down(lC, off, 64);
            lS += __shfl_down(lS, off, 64);
            lZ += __shfl_down(lZ, off, 64);
        }
        __shared__ double dred[3 * (THREADS / 64)];
        if (lane == 0) { dred[wid * 3] = lC; dred[wid * 3 + 1] = lS; dred[wid * 3 + 2] = lZ; }
        __syncthreads();
        if (threadIdx.x == 0) {
            double c = 0.0, sp = 0.0, z = 0.0;
#pragma unroll
            for (int w = 0; w < THREADS / 64; ++w) {
                c += dred[w * 3]; sp += dred[w * 3 + 1]; z += dred[w * 3 + 2];
            }
            z -= (double)n;  // remove self-pairs (each contributes ~1.0)
            out[0] = (float)(c + sp * log(z));
        }
    }
}

extern "C" void kernel_launch(void* const* d_in, const int* in_sizes, int n_in,
                              void* d_out, int out_size, void* d_ws, size_t ws_size,
                              hipStream_t stream) {
    const float* emb  = (const float*)d_in[0];
    const float* p    = (const float*)d_in[1];
    const int* heads  = (const int*)d_in[2];
    const int* tails  = (const int*)d_in[3];
    const int n = in_sizes[0] / 2;   // 32768 points (D=2)
    const int e = in_sizes[1];       // edge count

    const int nt = n / TJ;                    // 64
    const int nbBlocks = nt * (nt + 1) / 2;   // 2080 upper-triangle tiles

    double* pZ = (double*)d_ws;
    double* pC = pZ + nbBlocks;
    double* pS = pC + EDGE_BLOCKS;
    int* flags = (int*)(pS + EDGE_BLOCKS);

    const int total = EDGE_BLOCKS + nbBlocks + 1;
    fused_kernel<<<total, THREADS, 0, stream>>>(emb, p, heads, tails, e, n, nt,
                                                nbBlocks, pZ, pC, pS, flags,
                                                (float*)d_out);
}